// Round 2
// baseline (1971.503 us; speedup 1.0000x reference)
//
#include <hip/hip_runtime.h>
#include <cstdint>

#define NA 20000
#define NE 80000

// per-l offsets (in floats) inside h / out buffers (atom-major, [n][i][j][c])
constexpr int HOFFc[4]   = {0, 2560000, 5120000, 10880000};
// packed rbm layout per edge: rbm0[128] rbm1[96] rbm2[64] rbm3[32]  (320 total)
constexpr int RBMOFFc[4] = {0, 128, 224, 288};
// global q (0..15) -> which l' the sh/rbm row comes from
constexpr int QLPc[16]   = {0,1,1,1,2,2,2,2,2,3,3,3,3,3,3,3};

// ---------------- Kernel 1: EquivariantRMSNorm + linear_in -> h ----------------
__global__ __launch_bounds__(256)
void k_norm_in(const float* __restrict__ f0, const float* __restrict__ f1,
               const float* __restrict__ f2, const float* __restrict__ f3,
               const float* __restrict__ gammas, const float* __restrict__ Win,
               float* __restrict__ h)
{
    const int l = blockIdx.y;
    const int S = (l < 2) ? 4 : ((l == 2) ? 9 : 16);
    const float* fsel = (l == 0) ? f0 : ((l == 1) ? f1 : ((l == 2) ? f2 : f3));
    float* hb = h + HOFFc[l];

    __shared__ float s_win[1024];
    __shared__ float s_g[32];
    __shared__ float s_fn[4][16][32];

    const int t = threadIdx.x;
    for (int i = t; i < 1024; i += 256) s_win[i] = Win[l * 1024 + i];
    if (t < 32) s_g[t] = gammas[l * 32 + t];
    __syncthreads();

    const int w = t >> 6, lane = t & 63, c = lane & 31, hlf = lane >> 5;
    const int n = blockIdx.x * 4 + w;
    const float* fp = fsel + (size_t)n * S * 32;

    float ss = 0.f;
    for (int s = hlf; s < S; s += 2) { float v = fp[s * 32 + c]; ss += v * v; }
    ss += __shfl_xor(ss, 32);
    const float scale = s_g[c] * rsqrtf(ss / (float)S + 1e-6f);

    for (int s = hlf; s < S; s += 2) s_fn[w][s][c] = fp[s * 32 + c] * scale;
    __syncthreads();

    float* hp = hb + (size_t)n * S * 32;
    for (int s = hlf; s < S; s += 2) {
        float acc = 0.f;
        #pragma unroll
        for (int ff = 0; ff < 32; ff++) acc += s_fn[w][s][ff] * s_win[ff * 32 + c];
        hp[s * 32 + c] = acc;
    }
}

// ---------------- phase A helper: hidden = silu(rb@A); rbm = hidden@B ----------------
template<int K>
__device__ __forceinline__ void phaseA(int t, const float* __restrict__ Ap,
                                       const float* __restrict__ Bp,
                                       const float (* __restrict__ s_rb_l)[32],
                                       float (* __restrict__ s_hid)[128],
                                       float (* __restrict__ s_rbm)[320], int rbmoff)
{
    const int e  = t >> 4;
    const int j0 = (t & 15) * 8;
    float acc[8] = {0.f,0.f,0.f,0.f,0.f,0.f,0.f,0.f};
    const float* Arow = Ap + j0;
    #pragma unroll 4
    for (int k = 0; k < 32; k++) {
        const float r = s_rb_l[e][k];
        const float4 a0 = *reinterpret_cast<const float4*>(Arow + k * 128);
        const float4 a1 = *reinterpret_cast<const float4*>(Arow + k * 128 + 4);
        acc[0] += r * a0.x; acc[1] += r * a0.y; acc[2] += r * a0.z; acc[3] += r * a0.w;
        acc[4] += r * a1.x; acc[5] += r * a1.y; acc[6] += r * a1.z; acc[7] += r * a1.w;
    }
    __syncthreads();
    #pragma unroll
    for (int u = 0; u < 8; u++) {
        const float x = acc[u];
        s_hid[e][j0 + u] = x / (1.f + __expf(-x));
    }
    __syncthreads();

    constexpr int W = K / 16;
    const int c0 = (t & 15) * W;
    float accb[W] = {};
    const float* Bb = Bp + c0;
    #pragma unroll 2
    for (int j = 0; j < 128; j++) {
        const float hv = s_hid[e][j];
        #pragma unroll
        for (int u = 0; u < W; u += 2) {
            const float2 b = *reinterpret_cast<const float2*>(Bb + j * K + u);
            accb[u] += hv * b.x; accb[u + 1] += hv * b.y;
        }
    }
    #pragma unroll
    for (int u = 0; u < W; u++) s_rbm[e][rbmoff + c0 + u] = accb[u];
}

// ---------------- Kernel 2 (new path): radial MLP -> rbm + packed sh -> shq ----------------
__global__ __launch_bounds__(256, 4)
void k_edgeA(const float* __restrict__ rb,
             const float* __restrict__ sh0, const float* __restrict__ sh1,
             const float* __restrict__ sh2, const float* __restrict__ sh3,
             const float* __restrict__ A,
             const float* __restrict__ B0, const float* __restrict__ B1,
             const float* __restrict__ B2, const float* __restrict__ B3,
             float* __restrict__ rbm, float* __restrict__ shq)
{
    __shared__ float s_rb[4][16][32];
    __shared__ float s_hid[16][128];
    __shared__ float s_rbm[16][320];

    const int t  = threadIdx.x;
    const int e0 = blockIdx.x * 16;

    for (int i = t; i < 2048; i += 256)
        (&s_rb[0][0][0])[i] = rb[(i >> 9) * (NE * 32) + e0 * 32 + (i & 511)];
    // packed sh write: thread t covers (e = t>>4, q = t&15)
    {
        const int e = t >> 4, q = t & 15, ge = e0 + e;
        float v;
        if (q == 0)      v = sh0[ge];
        else if (q < 4)  v = sh1[ge * 3 + (q - 1)];
        else if (q < 9)  v = sh2[ge * 5 + (q - 4)];
        else             v = sh3[ge * 7 + (q - 9)];
        shq[e0 * 16 + t] = v;
    }
    __syncthreads();

    phaseA<128>(t, A,         B0, s_rb[0], s_hid, s_rbm, 0);
    phaseA< 96>(t, A +  4096, B1, s_rb[1], s_hid, s_rbm, 128);
    phaseA< 64>(t, A +  8192, B2, s_rb[2], s_hid, s_rbm, 224);
    phaseA< 32>(t, A + 12288, B3, s_rb[3], s_hid, s_rbm, 288);
    __syncthreads();

    const float* src = &s_rbm[0][0];
    for (int i = t; i < 5120; i += 256) rbm[(size_t)e0 * 320 + i] = src[i];
}

// ---------------- CSR build ----------------
__global__ __launch_bounds__(256)
void k_hist(const int* __restrict__ centers, int* __restrict__ counts)
{
    const int e = blockIdx.x * 256 + threadIdx.x;
    if (e < NE) atomicAdd(&counts[centers[e]], 1);
}

__global__ __launch_bounds__(1024)
void k_scan(const int* __restrict__ counts, int* __restrict__ offsets)
{
    __shared__ int s_sum[1024];
    const int t = threadIdx.x;
    const int CH = 20;
    const int base = t * CH;
    int n = NA - base; n = n < 0 ? 0 : (n > CH ? CH : n);

    int tot = 0;
    for (int i = 0; i < n; i++) tot += counts[base + i];
    s_sum[t] = tot;
    __syncthreads();
    for (int off = 1; off < 1024; off <<= 1) {
        int v = (t >= off) ? s_sum[t - off] : 0;
        __syncthreads();
        s_sum[t] += v;
        __syncthreads();
    }
    int run = s_sum[t] - tot;   // exclusive prefix of this thread's chunk
    for (int i = 0; i < n; i++) { offsets[base + i] = run; run += counts[base + i]; }
    if (t == 0) offsets[NA] = NE;
}

__global__ __launch_bounds__(256)
void k_fill(const int* __restrict__ centers, const int* __restrict__ offsets,
            int* __restrict__ cursor, int* __restrict__ elist)
{
    const int e = blockIdx.x * 256 + threadIdx.x;
    if (e < NE) {
        const int ctr = centers[e];
        const int pos = offsets[ctr] + atomicAdd(&cursor[ctr], 1);
        elist[pos] = e;
    }
}

// ---------------- Kernel 3 (new path): gather-pool + Wout + residual ----------------
template<int L, int LOWER, int P1, int VQ>
__device__ __forceinline__ void pool_group(
    const float* __restrict__ sU, const float* __restrict__ s_woutl,
    float* __restrict__ s_accw,
    const float* __restrict__ shq, const float* __restrict__ rbm,
    const float* __restrict__ hL, const float* __restrict__ fL,
    float* __restrict__ outL,
    const int* __restrict__ elist, const int* __restrict__ neighbors,
    int beg, int end, int n, int c, int half, float ms)
{
    constexpr int S = P1 * P1;
    float acc[S];
    #pragma unroll
    for (int s = 0; s < S; s++) acc[s] = 0.f;

    const int nit = (end - beg + 1) >> 1;   // halves split the edge list
    for (int it = 0; it < nit; ++it) {
        const int slot = beg + it * 2 + half;
        const bool valid = slot < end;
        const int e   = elist[valid ? slot : beg];
        const int nbr = neighbors[e];
        const float fac = valid ? 1.f : 0.f;

        float rv[L + 1];
        #pragma unroll
        for (int lp = 0; lp <= L; lp++)
            rv[lp] = fac * rbm[(size_t)e * 320 + RBMOFFc[lp] + LOWER + c];

        float st[VQ];
        #pragma unroll
        for (int q = 0; q < VQ; q++)
            st[q] = shq[e * 16 + q] * rv[QLPc[q]];

        float unc[S];
        #pragma unroll
        for (int p = 0; p < S; p++) {
            float a = 0.f;
            #pragma unroll
            for (int q = 0; q < VQ; q++) a += sU[p * S + q] * st[q];
            unc[p] = a;
        }

        float hn[S];
        const float* hp = hL + (size_t)nbr * (S * 32) + c;
        #pragma unroll
        for (int p = 0; p < S; p++) hn[p] = hp[p * 32];

        #pragma unroll
        for (int i = 0; i < P1; i++) {
            #pragma unroll
            for (int k = 0; k < P1; k++) {
                float m = 0.f;
                #pragma unroll
                for (int j = 0; j < P1; j++) m += unc[i * P1 + j] * hn[j * P1 + k];
                acc[i * P1 + k] += m;
            }
        }
    }

    // combine the two halves' partial sums
    #pragma unroll
    for (int s = 0; s < S; s++) acc[s] += __shfl_xor(acc[s], 32);

    // stage to per-wave LDS for the cross-channel linear
    #pragma unroll
    for (int s = 0; s < S; s++) if ((s & 1) == half) s_accw[s * 32 + c] = acc[s];
    __syncthreads();

    const float* fp = fL + (size_t)n * (S * 32);
    float* op = outL + (size_t)n * (S * 32);
    for (int s = half; s < S; s += 2) {
        float o = 0.f;
        #pragma unroll
        for (int f = 0; f < 32; f++) o += s_accw[s * 32 + f] * s_woutl[f * 32 + c];
        op[s * 32 + c] = fp[s * 32 + c] + ms * o;
    }
    __syncthreads();
}

__global__ __launch_bounds__(256, 4)
void k_pool_out(const float* __restrict__ f0, const float* __restrict__ f1,
                const float* __restrict__ f2, const float* __restrict__ f3,
                const float* __restrict__ U1, const float* __restrict__ U2,
                const float* __restrict__ U3, const float* __restrict__ Wout,
                const float* __restrict__ msp,
                const float* __restrict__ shq, const float* __restrict__ rbm,
                const float* __restrict__ h,
                const int* __restrict__ offsets, const int* __restrict__ elist,
                const int* __restrict__ neighbors, float* __restrict__ out)
{
    __shared__ float s_U[353];          // U3[256] U2[81] U1[16], pre-scaled by 1/sqrt(P+1)
    __shared__ float s_wout[4096];
    __shared__ float s_acc[4][16 * 32]; // per-wave scratch

    const int t = threadIdx.x;
    for (int i = t; i < 353; i += 256) {
        float v;
        if (i < 256)      v = U3[i]       * 0.5f;
        else if (i < 337) v = U2[i - 256] * 0.57735026918962576f;
        else              v = U1[i - 337] * 0.70710678118654752f;
        s_U[i] = v;
    }
    for (int i = t; i < 4096; i += 256) s_wout[i] = Wout[i];
    __syncthreads();

    const int w = t >> 6, lane = t & 63, c = lane & 31, half = lane >> 5;
    const int n = blockIdx.x * 4 + w;
    const float ms = *msp;
    const int beg = offsets[n], end = offsets[n + 1];

    pool_group<0, 96, 2,  1>(s_U + 337, s_wout,        s_acc[w], shq, rbm, h + HOFFc[0], f0, out + HOFFc[0], elist, neighbors, beg, end, n, c, half, ms);
    pool_group<1, 64, 2,  4>(s_U + 337, s_wout + 1024, s_acc[w], shq, rbm, h + HOFFc[1], f1, out + HOFFc[1], elist, neighbors, beg, end, n, c, half, ms);
    pool_group<2, 32, 3,  9>(s_U + 256, s_wout + 2048, s_acc[w], shq, rbm, h + HOFFc[2], f2, out + HOFFc[2], elist, neighbors, beg, end, n, c, half, ms);
    pool_group<3,  0, 4, 16>(s_U,       s_wout + 3072, s_acc[w], shq, rbm, h + HOFFc[3], f3, out + HOFFc[3], elist, neighbors, beg, end, n, c, half, ms);
}

// =====================================================================
// ============ FALLBACK PATH (round-1 kernels, atomics) ===============
// =====================================================================
template<int LOWERV, int P1, int VQ>
__device__ __forceinline__ void tp_group(const float* __restrict__ sU,
                                         const float* __restrict__ she,
                                         const float* __restrict__ rbme,
                                         const float* __restrict__ hL,
                                         float* __restrict__ pL,
                                         int nbr, int ctr, int c)
{
    constexpr int S = P1 * P1;
    float st[VQ];
    #pragma unroll
    for (int q = 0; q < VQ; q++)
        st[q] = she[q] * rbme[RBMOFFc[QLPc[q]] + LOWERV + c];

    float unc[S];
    #pragma unroll
    for (int p = 0; p < S; p++) {
        float a = 0.f;
        #pragma unroll
        for (int q = 0; q < VQ; q++) a += sU[p * S + q] * st[q];
        unc[p] = a;
    }

    const float* hp = hL + (size_t)nbr * (S * 32) + c;
    float hn[S];
    #pragma unroll
    for (int p = 0; p < S; p++) hn[p] = hp[p * 32];

    float* pp = pL + (size_t)ctr * (S * 32) + c;
    #pragma unroll
    for (int i = 0; i < P1; i++) {
        #pragma unroll
        for (int k = 0; k < P1; k++) {
            float m = 0.f;
            #pragma unroll
            for (int j = 0; j < P1; j++) m += unc[i * P1 + j] * hn[j * P1 + k];
            atomicAdd(pp + (i * P1 + k) * 32, m);
        }
    }
}

__global__ __launch_bounds__(256)
void k_edge(const float* __restrict__ rb,
            const float* __restrict__ sh0, const float* __restrict__ sh1,
            const float* __restrict__ sh2, const float* __restrict__ sh3,
            const float* __restrict__ U1, const float* __restrict__ U2,
            const float* __restrict__ U3, const float* __restrict__ A,
            const float* __restrict__ B0, const float* __restrict__ B1,
            const float* __restrict__ B2, const float* __restrict__ B3,
            const int* __restrict__ centers, const int* __restrict__ neighbors,
            const float* __restrict__ h, float* __restrict__ pooled)
{
    __shared__ float s_rb[4][16][32];
    __shared__ float s_hid[16][128];
    __shared__ float s_rbm[16][320];
    __shared__ float s_sh[16][16];
    __shared__ float s_U[353];
    __shared__ int   s_nbr[16];
    __shared__ int   s_ctr[16];

    const int t  = threadIdx.x;
    const int e0 = blockIdx.x * 16;

    for (int i = t; i < 2048; i += 256)
        (&s_rb[0][0][0])[i] = rb[(i >> 9) * (NE * 32) + e0 * 32 + (i & 511)];
    {
        const int e = t >> 4, q = t & 15, ge = e0 + e;
        float v;
        if (q == 0)      v = sh0[ge];
        else if (q < 4)  v = sh1[ge * 3 + (q - 1)];
        else if (q < 9)  v = sh2[ge * 5 + (q - 4)];
        else             v = sh3[ge * 7 + (q - 9)];
        s_sh[e][q] = v;
    }
    for (int i = t; i < 353; i += 256) {
        float v;
        if (i < 256)      v = U3[i]       * 0.5f;
        else if (i < 337) v = U2[i - 256] * 0.57735026918962576f;
        else              v = U1[i - 337] * 0.70710678118654752f;
        s_U[i] = v;
    }
    if (t < 16) { s_nbr[t] = neighbors[e0 + t]; s_ctr[t] = centers[e0 + t]; }
    __syncthreads();

    phaseA<128>(t, A,         B0, s_rb[0], s_hid, s_rbm, 0);
    phaseA< 96>(t, A +  4096, B1, s_rb[1], s_hid, s_rbm, 128);
    phaseA< 64>(t, A +  8192, B2, s_rb[2], s_hid, s_rbm, 224);
    phaseA< 32>(t, A + 12288, B3, s_rb[3], s_hid, s_rbm, 288);
    __syncthreads();

    const int ch = t & 31;
    #pragma unroll
    for (int eb = 0; eb < 16; eb += 8) {
        const int ee  = eb + (t >> 5);
        const int nbr = s_nbr[ee], ctr = s_ctr[ee];
        tp_group<96, 2,  1>(s_U + 337, s_sh[ee], s_rbm[ee], h,            pooled,            nbr, ctr, ch);
        tp_group<64, 2,  4>(s_U + 337, s_sh[ee], s_rbm[ee], h +  2560000, pooled +  2560000, nbr, ctr, ch);
        tp_group<32, 3,  9>(s_U + 256, s_sh[ee], s_rbm[ee], h +  5120000, pooled +  5120000, nbr, ctr, ch);
        tp_group< 0, 4, 16>(s_U,       s_sh[ee], s_rbm[ee], h + 10880000, pooled + 10880000, nbr, ctr, ch);
    }
}

__global__ __launch_bounds__(256)
void k_out(const float* __restrict__ f0, const float* __restrict__ f1,
           const float* __restrict__ f2, const float* __restrict__ f3,
           const float* __restrict__ Wout, const float* __restrict__ msp,
           const float* __restrict__ pooled, float* __restrict__ out)
{
    const int l = blockIdx.y;
    const int S = (l < 2) ? 4 : ((l == 2) ? 9 : 16);
    const float* fsel = (l == 0) ? f0 : ((l == 1) ? f1 : ((l == 2) ? f2 : f3));

    __shared__ float s_w[1024];
    __shared__ float s_p[4][16][32];

    const int t = threadIdx.x;
    for (int i = t; i < 1024; i += 256) s_w[i] = Wout[l * 1024 + i];
    __syncthreads();

    const float ms = *msp;
    const int w = t >> 6, lane = t & 63, c = lane & 31, hlf = lane >> 5;
    const int n = blockIdx.x * 4 + w;

    const float* pp = pooled + HOFFc[l] + (size_t)n * S * 32;
    for (int s = hlf; s < S; s += 2) s_p[w][s][c] = pp[s * 32 + c];
    __syncthreads();

    const float* fp = fsel + (size_t)n * S * 32;
    float* op = out + HOFFc[l] + (size_t)n * S * 32;
    for (int s = hlf; s < S; s += 2) {
        float acc = 0.f;
        #pragma unroll
        for (int ff = 0; ff < 32; ff++) acc += s_p[w][s][ff] * s_w[ff * 32 + c];
        op[s * 32 + c] = fp[s * 32 + c] + ms * acc;
    }
}

// =====================================================================
extern "C" void kernel_launch(void* const* d_in, const int* in_sizes, int n_in,
                              void* d_out, int out_size, void* d_ws, size_t ws_size,
                              hipStream_t stream)
{
    (void)in_sizes; (void)n_in; (void)out_size;

    const float* rb     = (const float*)d_in[0];
    const float* sh0    = (const float*)d_in[1];
    const float* sh1    = (const float*)d_in[2];
    const float* sh2    = (const float*)d_in[3];
    const float* sh3    = (const float*)d_in[4];
    const float* f0     = (const float*)d_in[5];
    const float* f1     = (const float*)d_in[6];
    const float* f2     = (const float*)d_in[7];
    const float* f3     = (const float*)d_in[8];
    const float* U1     = (const float*)d_in[9];
    const float* U2     = (const float*)d_in[10];
    const float* U3     = (const float*)d_in[11];
    const float* gammas = (const float*)d_in[12];
    const float* Win    = (const float*)d_in[13];
    const float* Wout   = (const float*)d_in[14];
    const float* A      = (const float*)d_in[15];
    const float* B0     = (const float*)d_in[16];
    const float* B1     = (const float*)d_in[17];
    const float* B2     = (const float*)d_in[18];
    const float* B3     = (const float*)d_in[19];
    const float* msp    = (const float*)d_in[20];
    const int* centers   = (const int*)d_in[21];
    const int* neighbors = (const int*)d_in[22];

    // new-path ws layout (floats):
    //   h    [21,120,000]
    //   rbm  [25,600,000]
    //   shq  [ 1,280,000]
    //   ints: offsets[20001] counts[20000] cursor[20000] elist[80000]
    const size_t F_H    = 0;
    const size_t F_RBM  = 21120000;
    const size_t F_SHQ  = F_RBM + 25600000;
    const size_t F_INT  = F_SHQ + 1280000;          // 48,000,000 floats
    const size_t needed_new = F_INT * 4 + (size_t)140001 * 4;
    const size_t needed_old = (size_t)2 * 21120000 * sizeof(float);

    float* h = (float*)d_ws;

    if (ws_size >= needed_new) {
        float* rbm = h + F_RBM;
        float* shq = h + F_SHQ;
        int* ibase   = (int*)(h + F_INT);
        int* offsets = ibase;            // 20001
        int* counts  = ibase + 20001;    // 20000
        int* cursor  = ibase + 40001;    // 20000
        int* elist   = ibase + 60001;    // 80000

        hipMemsetAsync(counts, 0, (size_t)40000 * sizeof(int), stream);  // counts + cursor

        k_hist<<<313, 256, 0, stream>>>(centers, counts);
        k_scan<<<1, 1024, 0, stream>>>(counts, offsets);
        k_fill<<<313, 256, 0, stream>>>(centers, offsets, cursor, elist);

        dim3 gA(5000, 4);
        k_norm_in<<<gA, 256, 0, stream>>>(f0, f1, f2, f3, gammas, Win, h);
        k_edgeA<<<5000, 256, 0, stream>>>(rb, sh0, sh1, sh2, sh3, A, B0, B1, B2, B3, rbm, shq);
        k_pool_out<<<5000, 256, 0, stream>>>(f0, f1, f2, f3, U1, U2, U3, Wout, msp,
                                             shq, rbm, h, offsets, elist, neighbors,
                                             (float*)d_out);
    } else if (ws_size >= needed_old) {
        float* pooled = h + 21120000;
        hipMemsetAsync(pooled, 0, (size_t)21120000 * sizeof(float), stream);
        dim3 gA(5000, 4);
        k_norm_in<<<gA, 256, 0, stream>>>(f0, f1, f2, f3, gammas, Win, h);
        k_edge<<<5000, 256, 0, stream>>>(rb, sh0, sh1, sh2, sh3, U1, U2, U3, A,
                                         B0, B1, B2, B3, centers, neighbors, h, pooled);
        k_out<<<gA, 256, 0, stream>>>(f0, f1, f2, f3, Wout, msp, pooled, (float*)d_out);
    }
}

// Round 3
// 1404.134 us; speedup vs baseline: 1.4041x; 1.4041x over previous
//
#include <hip/hip_runtime.h>
#include <cstdint>

#define NA 20000
#define NE 80000

// per-l offsets (in floats) inside h / out buffers (atom-major, [n][i][j][c])
constexpr int HOFFc[4]   = {0, 2560000, 5120000, 10880000};
// packed rbm layout per edge: rbm0[128] rbm1[96] rbm2[64] rbm3[32]  (320 total)
constexpr int RBMOFFc[4] = {0, 128, 224, 288};
// global q (0..15) -> which l' the sh/rbm row comes from
constexpr int QLPc[16]   = {0,1,1,1,2,2,2,2,2,3,3,3,3,3,3,3};

// ---------------- Kernel 1: EquivariantRMSNorm + linear_in -> h ----------------
__global__ __launch_bounds__(256)
void k_norm_in(const float* __restrict__ f0, const float* __restrict__ f1,
               const float* __restrict__ f2, const float* __restrict__ f3,
               const float* __restrict__ gammas, const float* __restrict__ Win,
               float* __restrict__ h)
{
    const int l = blockIdx.y;
    const int S = (l < 2) ? 4 : ((l == 2) ? 9 : 16);
    const float* fsel = (l == 0) ? f0 : ((l == 1) ? f1 : ((l == 2) ? f2 : f3));
    float* hb = h + HOFFc[l];

    __shared__ float s_win[1024];
    __shared__ float s_g[32];
    __shared__ float s_fn[4][16][32];

    const int t = threadIdx.x;
    for (int i = t; i < 1024; i += 256) s_win[i] = Win[l * 1024 + i];
    if (t < 32) s_g[t] = gammas[l * 32 + t];
    __syncthreads();

    const int w = t >> 6, lane = t & 63, c = lane & 31, hlf = lane >> 5;
    const int n = blockIdx.x * 4 + w;
    const float* fp = fsel + (size_t)n * S * 32;

    float ss = 0.f;
    for (int s = hlf; s < S; s += 2) { float v = fp[s * 32 + c]; ss += v * v; }
    ss += __shfl_xor(ss, 32);
    const float scale = s_g[c] * rsqrtf(ss / (float)S + 1e-6f);

    for (int s = hlf; s < S; s += 2) s_fn[w][s][c] = fp[s * 32 + c] * scale;
    __syncthreads();

    float* hp = hb + (size_t)n * S * 32;
    for (int s = hlf; s < S; s += 2) {
        float acc = 0.f;
        #pragma unroll
        for (int ff = 0; ff < 32; ff++) acc += s_fn[w][s][ff] * s_win[ff * 32 + c];
        hp[s * 32 + c] = acc;
    }
}

// ---------------- phase A helper: hidden = silu(rb@A); rbm = hidden@B ----------------
template<int K>
__device__ __forceinline__ void phaseA(int t, const float* __restrict__ Ap,
                                       const float* __restrict__ Bp,
                                       const float (* __restrict__ s_rb_l)[32],
                                       float (* __restrict__ s_hid)[128],
                                       float (* __restrict__ s_rbm)[320], int rbmoff)
{
    const int e  = t >> 4;
    const int j0 = (t & 15) * 8;
    float acc[8] = {0.f,0.f,0.f,0.f,0.f,0.f,0.f,0.f};
    const float* Arow = Ap + j0;
    #pragma unroll 4
    for (int k = 0; k < 32; k++) {
        const float r = s_rb_l[e][k];
        const float4 a0 = *reinterpret_cast<const float4*>(Arow + k * 128);
        const float4 a1 = *reinterpret_cast<const float4*>(Arow + k * 128 + 4);
        acc[0] += r * a0.x; acc[1] += r * a0.y; acc[2] += r * a0.z; acc[3] += r * a0.w;
        acc[4] += r * a1.x; acc[5] += r * a1.y; acc[6] += r * a1.z; acc[7] += r * a1.w;
    }
    __syncthreads();
    #pragma unroll
    for (int u = 0; u < 8; u++) {
        const float x = acc[u];
        s_hid[e][j0 + u] = x / (1.f + __expf(-x));
    }
    __syncthreads();

    constexpr int W = K / 16;
    const int c0 = (t & 15) * W;
    float accb[W] = {};
    const float* Bb = Bp + c0;
    #pragma unroll 2
    for (int j = 0; j < 128; j++) {
        const float hv = s_hid[e][j];
        #pragma unroll
        for (int u = 0; u < W; u += 2) {
            const float2 b = *reinterpret_cast<const float2*>(Bb + j * K + u);
            accb[u] += hv * b.x; accb[u + 1] += hv * b.y;
        }
    }
    #pragma unroll
    for (int u = 0; u < W; u++) s_rbm[e][rbmoff + c0 + u] = accb[u];
}

// ---------------- Kernel 2: radial MLP -> rbm + packed sh -> shq ----------------
__global__ __launch_bounds__(256, 4)
void k_edgeA(const float* __restrict__ rb,
             const float* __restrict__ sh0, const float* __restrict__ sh1,
             const float* __restrict__ sh2, const float* __restrict__ sh3,
             const float* __restrict__ A,
             const float* __restrict__ B0, const float* __restrict__ B1,
             const float* __restrict__ B2, const float* __restrict__ B3,
             float* __restrict__ rbm, float* __restrict__ shq)
{
    __shared__ float s_rb[4][16][32];
    __shared__ float s_hid[16][128];
    __shared__ float s_rbm[16][320];

    const int t  = threadIdx.x;
    const int e0 = blockIdx.x * 16;

    for (int i = t; i < 2048; i += 256)
        (&s_rb[0][0][0])[i] = rb[(i >> 9) * (NE * 32) + e0 * 32 + (i & 511)];
    {
        const int e = t >> 4, q = t & 15, ge = e0 + e;
        float v;
        if (q == 0)      v = sh0[ge];
        else if (q < 4)  v = sh1[ge * 3 + (q - 1)];
        else if (q < 9)  v = sh2[ge * 5 + (q - 4)];
        else             v = sh3[ge * 7 + (q - 9)];
        shq[e0 * 16 + t] = v;
    }
    __syncthreads();

    phaseA<128>(t, A,         B0, s_rb[0], s_hid, s_rbm, 0);
    phaseA< 96>(t, A +  4096, B1, s_rb[1], s_hid, s_rbm, 128);
    phaseA< 64>(t, A +  8192, B2, s_rb[2], s_hid, s_rbm, 224);
    phaseA< 32>(t, A + 12288, B3, s_rb[3], s_hid, s_rbm, 288);
    __syncthreads();

    const float* src = &s_rbm[0][0];
    for (int i = t; i < 5120; i += 256) rbm[(size_t)e0 * 320 + i] = src[i];
}

// ---------------- CSR build ----------------
__global__ __launch_bounds__(256)
void k_hist(const int* __restrict__ centers, int* __restrict__ counts)
{
    const int e = blockIdx.x * 256 + threadIdx.x;
    if (e < NE) atomicAdd(&counts[centers[e]], 1);
}

__global__ __launch_bounds__(1024)
void k_scan(const int* __restrict__ counts, int* __restrict__ offsets)
{
    __shared__ int s_sum[1024];
    const int t = threadIdx.x;
    const int CH = 20;
    const int base = t * CH;
    int n = NA - base; n = n < 0 ? 0 : (n > CH ? CH : n);

    int tot = 0;
    for (int i = 0; i < n; i++) tot += counts[base + i];
    s_sum[t] = tot;
    __syncthreads();
    for (int off = 1; off < 1024; off <<= 1) {
        int v = (t >= off) ? s_sum[t - off] : 0;
        __syncthreads();
        s_sum[t] += v;
        __syncthreads();
    }
    int run = s_sum[t] - tot;
    for (int i = 0; i < n; i++) { offsets[base + i] = run; run += counts[base + i]; }
    if (t == 0) offsets[NA] = NE;
}

__global__ __launch_bounds__(256)
void k_fill(const int* __restrict__ centers, const int* __restrict__ offsets,
            int* __restrict__ cursor, int* __restrict__ elist)
{
    const int e = blockIdx.x * 256 + threadIdx.x;
    if (e < NE) {
        const int ctr = centers[e];
        const int pos = offsets[ctr] + atomicAdd(&cursor[ctr], 1);
        elist[pos] = e;
    }
}

// ---------------- per-l pool kernels: gather + uncouple + TP + Wout + residual ----------------
// One wave per atom; halves of the wave split the atom's edge list; row-by-row
// uncouple (ur[P1]) keeps peak live registers ~50 floats for l=3 -> no spill.
template<int L, int LOWER, int P1, int VQ>
__device__ __forceinline__ void pool_body(
    const float* __restrict__ Up, float uscale,
    const float* __restrict__ WoutL, const float* __restrict__ msp,
    const float* __restrict__ shq, const float* __restrict__ rbm,
    const float* __restrict__ hL, const float* __restrict__ fL,
    float* __restrict__ outL,
    const int* __restrict__ offsets, const int* __restrict__ elist,
    const int* __restrict__ neighbors)
{
    constexpr int S = P1 * P1;
    __shared__ float s_U[S * S];
    __shared__ float s_w[1024];
    __shared__ float s_acc[4][S * 32];

    const int t = threadIdx.x;
    for (int i = t; i < S * S; i += 256) s_U[i] = Up[i] * uscale;
    for (int i = t; i < 1024; i += 256) s_w[i] = WoutL[i];
    __syncthreads();

    const int w = t >> 6, lane = t & 63, c = lane & 31, half = lane >> 5;
    const int n = blockIdx.x * 4 + w;
    const float ms = *msp;
    const int beg = offsets[n], end = offsets[n + 1];

    float acc[S];
    #pragma unroll
    for (int s = 0; s < S; s++) acc[s] = 0.f;

    const int nit = (end - beg + 1) >> 1;   // halves split the edge list
    for (int it = 0; it < nit; ++it) {
        const int slot = beg + it * 2 + half;
        const bool valid = slot < end;
        const int e   = elist[valid ? slot : beg];
        const int nbr = neighbors[e];
        const float fac = valid ? 1.f : 0.f;

        float rv[L + 1];
        #pragma unroll
        for (int lp = 0; lp <= L; lp++)
            rv[lp] = fac * rbm[(size_t)e * 320 + RBMOFFc[lp] + LOWER + c];

        float st[VQ];
        #pragma unroll
        for (int q = 0; q < VQ; q++)
            st[q] = shq[e * 16 + q] * rv[QLPc[q]];

        float hn[S];
        const float* hp = hL + (size_t)nbr * (S * 32) + c;
        #pragma unroll
        for (int p = 0; p < S; p++) hn[p] = hp[p * 32];

        #pragma unroll
        for (int i = 0; i < P1; i++) {
            float ur[P1];
            #pragma unroll
            for (int j = 0; j < P1; j++) {
                float a = 0.f;
                #pragma unroll
                for (int q = 0; q < VQ; q++) a += s_U[(i * P1 + j) * S + q] * st[q];
                ur[j] = a;
            }
            #pragma unroll
            for (int k = 0; k < P1; k++) {
                float m = 0.f;
                #pragma unroll
                for (int j = 0; j < P1; j++) m += ur[j] * hn[j * P1 + k];
                acc[i * P1 + k] += m;
            }
        }
    }

    // combine halves
    #pragma unroll
    for (int s = 0; s < S; s++) acc[s] += __shfl_xor(acc[s], 32);

    // stage to per-wave LDS for the cross-channel linear
    #pragma unroll
    for (int s = 0; s < S; s++) if ((s & 1) == half) s_acc[w][s * 32 + c] = acc[s];
    __syncthreads();

    const float* fp = fL + (size_t)n * (S * 32);
    float* op = outL + (size_t)n * (S * 32);
    for (int s = half; s < S; s += 2) {
        float o = 0.f;
        #pragma unroll
        for (int f = 0; f < 32; f++) o += s_acc[w][s * 32 + f] * s_w[f * 32 + c];
        op[s * 32 + c] = fp[s * 32 + c] + ms * o;
    }
}

__global__ __launch_bounds__(256, 2)
void k_pool_l0(const float* __restrict__ U1, const float* __restrict__ Wout,
               const float* __restrict__ msp, const float* __restrict__ shq,
               const float* __restrict__ rbm, const float* __restrict__ h,
               const float* __restrict__ f0, float* __restrict__ out,
               const int* __restrict__ offsets, const int* __restrict__ elist,
               const int* __restrict__ neighbors)
{
    pool_body<0, 96, 2, 1>(U1, 0.70710678118654752f, Wout, msp, shq, rbm,
                           h + HOFFc[0], f0, out + HOFFc[0], offsets, elist, neighbors);
}

__global__ __launch_bounds__(256, 2)
void k_pool_l1(const float* __restrict__ U1, const float* __restrict__ Wout,
               const float* __restrict__ msp, const float* __restrict__ shq,
               const float* __restrict__ rbm, const float* __restrict__ h,
               const float* __restrict__ f1, float* __restrict__ out,
               const int* __restrict__ offsets, const int* __restrict__ elist,
               const int* __restrict__ neighbors)
{
    pool_body<1, 64, 2, 4>(U1, 0.70710678118654752f, Wout + 1024, msp, shq, rbm,
                           h + HOFFc[1], f1, out + HOFFc[1], offsets, elist, neighbors);
}

__global__ __launch_bounds__(256, 2)
void k_pool_l2(const float* __restrict__ U2, const float* __restrict__ Wout,
               const float* __restrict__ msp, const float* __restrict__ shq,
               const float* __restrict__ rbm, const float* __restrict__ h,
               const float* __restrict__ f2, float* __restrict__ out,
               const int* __restrict__ offsets, const int* __restrict__ elist,
               const int* __restrict__ neighbors)
{
    pool_body<2, 32, 3, 9>(U2, 0.57735026918962576f, Wout + 2048, msp, shq, rbm,
                           h + HOFFc[2], f2, out + HOFFc[2], offsets, elist, neighbors);
}

__global__ __launch_bounds__(256, 2)
void k_pool_l3(const float* __restrict__ U3, const float* __restrict__ Wout,
               const float* __restrict__ msp, const float* __restrict__ shq,
               const float* __restrict__ rbm, const float* __restrict__ h,
               const float* __restrict__ f3, float* __restrict__ out,
               const int* __restrict__ offsets, const int* __restrict__ elist,
               const int* __restrict__ neighbors)
{
    pool_body<3, 0, 4, 16>(U3, 0.5f, Wout + 3072, msp, shq, rbm,
                           h + HOFFc[3], f3, out + HOFFc[3], offsets, elist, neighbors);
}

// =====================================================================
extern "C" void kernel_launch(void* const* d_in, const int* in_sizes, int n_in,
                              void* d_out, int out_size, void* d_ws, size_t ws_size,
                              hipStream_t stream)
{
    (void)in_sizes; (void)n_in; (void)out_size;

    const float* rb     = (const float*)d_in[0];
    const float* sh0    = (const float*)d_in[1];
    const float* sh1    = (const float*)d_in[2];
    const float* sh2    = (const float*)d_in[3];
    const float* sh3    = (const float*)d_in[4];
    const float* f0     = (const float*)d_in[5];
    const float* f1     = (const float*)d_in[6];
    const float* f2     = (const float*)d_in[7];
    const float* f3     = (const float*)d_in[8];
    const float* U1     = (const float*)d_in[9];
    const float* U2     = (const float*)d_in[10];
    const float* U3     = (const float*)d_in[11];
    const float* gammas = (const float*)d_in[12];
    const float* Win    = (const float*)d_in[13];
    const float* Wout   = (const float*)d_in[14];
    const float* A      = (const float*)d_in[15];
    const float* B0     = (const float*)d_in[16];
    const float* B1     = (const float*)d_in[17];
    const float* B2     = (const float*)d_in[18];
    const float* B3     = (const float*)d_in[19];
    const float* msp    = (const float*)d_in[20];
    const int* centers   = (const int*)d_in[21];
    const int* neighbors = (const int*)d_in[22];

    // ws layout (floats): h[21.12M] rbm[25.6M] shq[1.28M] + ints
    const size_t F_RBM  = 21120000;
    const size_t F_SHQ  = F_RBM + 25600000;
    const size_t F_INT  = F_SHQ + 1280000;
    const size_t needed = F_INT * 4 + (size_t)140001 * 4;
    if (ws_size < needed) return;

    float* h   = (float*)d_ws;
    float* rbm = h + F_RBM;
    float* shq = h + F_SHQ;
    int* ibase   = (int*)(h + F_INT);
    int* offsets = ibase;            // 20001
    int* counts  = ibase + 20001;    // 20000
    int* cursor  = ibase + 40001;    // 20000
    int* elist   = ibase + 60001;    // 80000

    hipMemsetAsync(counts, 0, (size_t)40000 * sizeof(int), stream);  // counts + cursor

    k_hist<<<313, 256, 0, stream>>>(centers, counts);
    k_scan<<<1, 1024, 0, stream>>>(counts, offsets);
    k_fill<<<313, 256, 0, stream>>>(centers, offsets, cursor, elist);

    dim3 gA(5000, 4);
    k_norm_in<<<gA, 256, 0, stream>>>(f0, f1, f2, f3, gammas, Win, h);
    k_edgeA<<<5000, 256, 0, stream>>>(rb, sh0, sh1, sh2, sh3, A, B0, B1, B2, B3, rbm, shq);

    float* out = (float*)d_out;
    k_pool_l0<<<5000, 256, 0, stream>>>(U1, Wout, msp, shq, rbm, h, f0, out, offsets, elist, neighbors);
    k_pool_l1<<<5000, 256, 0, stream>>>(U1, Wout, msp, shq, rbm, h, f1, out, offsets, elist, neighbors);
    k_pool_l2<<<5000, 256, 0, stream>>>(U2, Wout, msp, shq, rbm, h, f2, out, offsets, elist, neighbors);
    k_pool_l3<<<5000, 256, 0, stream>>>(U3, Wout, msp, shq, rbm, h, f3, out, offsets, elist, neighbors);
}

// Round 4
// 1081.018 us; speedup vs baseline: 1.8237x; 1.2989x over previous
//
#include <hip/hip_runtime.h>
#include <hip/hip_bf16.h>
#include <cstdint>

#define NA 20000
#define NE 80000

using bf16 = __hip_bfloat16;

// per-l offsets (in ELEMENTS) inside h / out buffers (atom-major, [n][i][j][c])
constexpr int HOFFc[4]   = {0, 2560000, 5120000, 10880000};
// packed rbm layout per edge: rbm0[128] rbm1[96] rbm2[64] rbm3[32]  (320 total)
constexpr int RBMOFFc[4] = {0, 128, 224, 288};
// global q (0..15) -> which l' the sh/rbm row comes from
constexpr int QLPc[16]   = {0,1,1,1,2,2,2,2,2,3,3,3,3,3,3,3};

// ---------------- Kernel 1: EquivariantRMSNorm + linear_in -> h (bf16) ----------------
__global__ __launch_bounds__(256)
void k_norm_in(const float* __restrict__ f0, const float* __restrict__ f1,
               const float* __restrict__ f2, const float* __restrict__ f3,
               const float* __restrict__ gammas, const float* __restrict__ Win,
               bf16* __restrict__ h)
{
    const int l = blockIdx.y;
    const int S = (l < 2) ? 4 : ((l == 2) ? 9 : 16);
    const float* fsel = (l == 0) ? f0 : ((l == 1) ? f1 : ((l == 2) ? f2 : f3));
    bf16* hb = h + HOFFc[l];

    __shared__ float s_win[1024];
    __shared__ float s_g[32];
    __shared__ float s_fn[4][16][32];

    const int t = threadIdx.x;
    for (int i = t; i < 1024; i += 256) s_win[i] = Win[l * 1024 + i];
    if (t < 32) s_g[t] = gammas[l * 32 + t];
    __syncthreads();

    const int w = t >> 6, lane = t & 63, c = lane & 31, hlf = lane >> 5;
    const int n = blockIdx.x * 4 + w;
    const float* fp = fsel + (size_t)n * S * 32;

    float ss = 0.f;
    for (int s = hlf; s < S; s += 2) { float v = fp[s * 32 + c]; ss += v * v; }
    ss += __shfl_xor(ss, 32);
    const float scale = s_g[c] * rsqrtf(ss / (float)S + 1e-6f);

    for (int s = hlf; s < S; s += 2) s_fn[w][s][c] = fp[s * 32 + c] * scale;
    __syncthreads();

    bf16* hp = hb + (size_t)n * S * 32;
    for (int s = hlf; s < S; s += 2) {
        float acc = 0.f;
        #pragma unroll
        for (int ff = 0; ff < 32; ff++) acc += s_fn[w][s][ff] * s_win[ff * 32 + c];
        hp[s * 32 + c] = __float2bfloat16(acc);
    }
}

// ---------------- Kernel 2: radial MLP as tiled SGEMM -> rbm (bf16) + shq ----------------
// 64 edges/block. Per l: phase1 hid = silu(rb@A) -> s_hT (transposed, XOR-swizzled),
// phase2 rbm = hid @ B_l via 64-col LDS B-tiles, 4x4 register blocking.
__global__ __launch_bounds__(256, 2)
void k_edgeA(const float* __restrict__ rb,
             const float* __restrict__ sh0, const float* __restrict__ sh1,
             const float* __restrict__ sh2, const float* __restrict__ sh3,
             const float* __restrict__ A,
             const float* __restrict__ B0, const float* __restrict__ B1,
             const float* __restrict__ B2, const float* __restrict__ B3,
             bf16* __restrict__ rbm, float* __restrict__ shq)
{
    __shared__ float sm[16384];            // 64 KB total
    float* s_rb = sm;                      // [64][33] = 2112   (phase1)
    float* s_A  = sm + 2112;               // [32][128] = 4096  (phase1)
    float* s_B  = sm;                      // [128][64] = 8192  (phase2; aliases rb+A)
    float* s_hT = sm + 8192;               // [128][64] = 8192  (swizzled hid^T)

    const int t  = threadIdx.x;
    const int e0 = blockIdx.x * 64;
    const int tx = t & 15, ty = t >> 4;

    // packed sh -> shq (64 edges x 16 q)
    for (int i = t; i < 1024; i += 256) {
        const int q = i & 15, ge = e0 + (i >> 4);
        float v;
        if (q == 0)      v = sh0[ge];
        else if (q < 4)  v = sh1[ge * 3 + (q - 1)];
        else if (q < 9)  v = sh2[ge * 5 + (q - 4)];
        else             v = sh3[ge * 7 + (q - 9)];
        shq[(size_t)e0 * 16 + i] = v;
    }

    const float* Bl[4] = {B0, B1, B2, B3};
    const int    Kl[4] = {128, 96, 64, 32};

    for (int l = 0; l < 4; ++l) {
        __syncthreads();   // prior phase2 done reading s_B region
        // ---- stage rb tile (coalesced, contiguous) + A_l ----
        for (int i = t; i < 2048; i += 256)
            s_rb[(i >> 5) * 33 + (i & 31)] = rb[(size_t)l * NE * 32 + (size_t)e0 * 32 + i];
        for (int i = t; i < 4096; i += 256)
            s_A[i] = A[l * 4096 + i];
        __syncthreads();

        // ---- phase1: hid[64][128] = silu(rb[64][32] @ A[32][128]) ----
        float a1[4][8];
        #pragma unroll
        for (int i = 0; i < 4; ++i)
            #pragma unroll
            for (int u = 0; u < 8; ++u) a1[i][u] = 0.f;

        #pragma unroll 4
        for (int k = 0; k < 32; ++k) {
            float rr[4];
            #pragma unroll
            for (int i = 0; i < 4; ++i) rr[i] = s_rb[(ty * 4 + i) * 33 + k];
            float av[8];
            *reinterpret_cast<float4*>(&av[0]) = *reinterpret_cast<const float4*>(&s_A[k * 128 + tx * 8]);
            *reinterpret_cast<float4*>(&av[4]) = *reinterpret_cast<const float4*>(&s_A[k * 128 + tx * 8 + 4]);
            #pragma unroll
            for (int i = 0; i < 4; ++i)
                #pragma unroll
                for (int u = 0; u < 8; ++u) a1[i][u] += rr[i] * av[u];
        }
        // silu + transposed store (b128 per col; XOR-swizzled e-block vs row j)
        #pragma unroll
        for (int u = 0; u < 8; ++u) {
            const int j = tx * 8 + u;
            float4 v;
            v.x = a1[0][u] / (1.f + __expf(-a1[0][u]));
            v.y = a1[1][u] / (1.f + __expf(-a1[1][u]));
            v.z = a1[2][u] / (1.f + __expf(-a1[2][u]));
            v.w = a1[3][u] / (1.f + __expf(-a1[3][u]));
            *reinterpret_cast<float4*>(&s_hT[j * 64 + ((ty ^ (j & 15)) << 2)]) = v;
        }
        __syncthreads();

        // ---- phase2: rbm_l[64][K] = hid @ B_l, 64-col tiles (zero-padded) ----
        const int K = Kl[l];
        const float* Bp = Bl[l];
        const int nt = (K + 63) >> 6;
        for (int ct = 0; ct < nt; ++ct) {
            const int c0 = ct * 64;
            for (int i = t; i < 8192; i += 256) {
                const int k = i >> 6, gc = c0 + (i & 63);
                s_B[i] = (gc < K) ? Bp[k * K + gc] : 0.f;
            }
            __syncthreads();

            float a2[4][4];
            #pragma unroll
            for (int i = 0; i < 4; ++i)
                #pragma unroll
                for (int j = 0; j < 4; ++j) a2[i][j] = 0.f;

            #pragma unroll 4
            for (int k = 0; k < 128; ++k) {
                float hv[4], bv[4];
                *reinterpret_cast<float4*>(hv) =
                    *reinterpret_cast<const float4*>(&s_hT[k * 64 + ((ty ^ (k & 15)) << 2)]);
                *reinterpret_cast<float4*>(bv) =
                    *reinterpret_cast<const float4*>(&s_B[k * 64 + (tx << 2)]);
                #pragma unroll
                for (int i = 0; i < 4; ++i)
                    #pragma unroll
                    for (int j = 0; j < 4; ++j) a2[i][j] += hv[i] * bv[j];
            }

            #pragma unroll
            for (int i = 0; i < 4; ++i) {
                const size_t eb = (size_t)(e0 + ty * 4 + i) * 320 + RBMOFFc[l] + c0 + tx * 4;
                #pragma unroll
                for (int j = 0; j < 4; ++j)
                    if (c0 + tx * 4 + j < K) rbm[eb + j] = __float2bfloat16(a2[i][j]);
            }
            __syncthreads();
        }
    }
}

// ---------------- CSR build ----------------
__global__ __launch_bounds__(256)
void k_hist(const int* __restrict__ centers, int* __restrict__ counts)
{
    const int e = blockIdx.x * 256 + threadIdx.x;
    if (e < NE) atomicAdd(&counts[centers[e]], 1);
}

__global__ __launch_bounds__(1024)
void k_scan(const int* __restrict__ counts, int* __restrict__ offsets)
{
    __shared__ int s_sum[1024];
    const int t = threadIdx.x;
    const int CH = 20;
    const int base = t * CH;
    int n = NA - base; n = n < 0 ? 0 : (n > CH ? CH : n);

    int tot = 0;
    for (int i = 0; i < n; i++) tot += counts[base + i];
    s_sum[t] = tot;
    __syncthreads();
    for (int off = 1; off < 1024; off <<= 1) {
        int v = (t >= off) ? s_sum[t - off] : 0;
        __syncthreads();
        s_sum[t] += v;
        __syncthreads();
    }
    int run = s_sum[t] - tot;
    for (int i = 0; i < n; i++) { offsets[base + i] = run; run += counts[base + i]; }
    if (t == 0) offsets[NA] = NE;
}

__global__ __launch_bounds__(256)
void k_fill(const int* __restrict__ centers, const int* __restrict__ offsets,
            int* __restrict__ cursor, int* __restrict__ elist)
{
    const int e = blockIdx.x * 256 + threadIdx.x;
    if (e < NE) {
        const int ctr = centers[e];
        const int pos = offsets[ctr] + atomicAdd(&cursor[ctr], 1);
        elist[pos] = e;
    }
}

// ---------------- per-l pool kernels: gather + uncouple + TP + Wout + residual ----------------
template<int L, int LOWER, int P1, int VQ>
__device__ __forceinline__ void pool_body(
    const float* __restrict__ Up, float uscale,
    const float* __restrict__ WoutL, const float* __restrict__ msp,
    const float* __restrict__ shq, const bf16* __restrict__ rbm,
    const bf16* __restrict__ hL, const float* __restrict__ fL,
    float* __restrict__ outL,
    const int* __restrict__ offsets, const int* __restrict__ elist,
    const int* __restrict__ neighbors)
{
    constexpr int S = P1 * P1;
    __shared__ float s_U[S * S];
    __shared__ float s_w[1024];
    __shared__ float s_acc[4][S * 32];

    const int t = threadIdx.x;
    for (int i = t; i < S * S; i += 256) s_U[i] = Up[i] * uscale;
    for (int i = t; i < 1024; i += 256) s_w[i] = WoutL[i];
    __syncthreads();

    const int w = t >> 6, lane = t & 63, c = lane & 31, half = lane >> 5;
    const int n = blockIdx.x * 4 + w;
    const float ms = *msp;
    const int beg = offsets[n], end = offsets[n + 1];

    float acc[S];
    #pragma unroll
    for (int s = 0; s < S; s++) acc[s] = 0.f;

    const int nit = (end - beg + 1) >> 1;   // halves split the edge list
    for (int it = 0; it < nit; ++it) {
        const int slot = beg + it * 2 + half;
        const bool valid = slot < end;
        const int e   = elist[valid ? slot : beg];
        const int nbr = neighbors[e];
        const float fac = valid ? 1.f : 0.f;

        float rv[L + 1];
        #pragma unroll
        for (int lp = 0; lp <= L; lp++)
            rv[lp] = fac * __bfloat162float(rbm[(size_t)e * 320 + RBMOFFc[lp] + LOWER + c]);

        float st[VQ];
        #pragma unroll
        for (int q = 0; q < VQ; q++)
            st[q] = shq[(size_t)e * 16 + q] * rv[QLPc[q]];

        float hn[S];
        const bf16* hp = hL + (size_t)nbr * (S * 32) + c;
        #pragma unroll
        for (int p = 0; p < S; p++) hn[p] = __bfloat162float(hp[p * 32]);

        #pragma unroll
        for (int i = 0; i < P1; i++) {
            float ur[P1];
            #pragma unroll
            for (int j = 0; j < P1; j++) {
                float a = 0.f;
                #pragma unroll
                for (int q = 0; q < VQ; q++) a += s_U[(i * P1 + j) * S + q] * st[q];
                ur[j] = a;
            }
            #pragma unroll
            for (int k = 0; k < P1; k++) {
                float m = 0.f;
                #pragma unroll
                for (int j = 0; j < P1; j++) m += ur[j] * hn[j * P1 + k];
                acc[i * P1 + k] += m;
            }
        }
    }

    // combine halves
    #pragma unroll
    for (int s = 0; s < S; s++) acc[s] += __shfl_xor(acc[s], 32);

    // stage to per-wave LDS for the cross-channel linear
    #pragma unroll
    for (int s = 0; s < S; s++) if ((s & 1) == half) s_acc[w][s * 32 + c] = acc[s];
    __syncthreads();

    const float* fp = fL + (size_t)n * (S * 32);
    float* op = outL + (size_t)n * (S * 32);
    for (int s = half; s < S; s += 2) {
        float o = 0.f;
        #pragma unroll
        for (int f = 0; f < 32; f++) o += s_acc[w][s * 32 + f] * s_w[f * 32 + c];
        op[s * 32 + c] = fp[s * 32 + c] + ms * o;
    }
}

__global__ __launch_bounds__(256, 2)
void k_pool_l0(const float* __restrict__ U1, const float* __restrict__ Wout,
               const float* __restrict__ msp, const float* __restrict__ shq,
               const bf16* __restrict__ rbm, const bf16* __restrict__ h,
               const float* __restrict__ f0, float* __restrict__ out,
               const int* __restrict__ offsets, const int* __restrict__ elist,
               const int* __restrict__ neighbors)
{
    pool_body<0, 96, 2, 1>(U1, 0.70710678118654752f, Wout, msp, shq, rbm,
                           h + HOFFc[0], f0, out + HOFFc[0], offsets, elist, neighbors);
}

__global__ __launch_bounds__(256, 2)
void k_pool_l1(const float* __restrict__ U1, const float* __restrict__ Wout,
               const float* __restrict__ msp, const float* __restrict__ shq,
               const bf16* __restrict__ rbm, const bf16* __restrict__ h,
               const float* __restrict__ f1, float* __restrict__ out,
               const int* __restrict__ offsets, const int* __restrict__ elist,
               const int* __restrict__ neighbors)
{
    pool_body<1, 64, 2, 4>(U1, 0.70710678118654752f, Wout + 1024, msp, shq, rbm,
                           h + HOFFc[1], f1, out + HOFFc[1], offsets, elist, neighbors);
}

__global__ __launch_bounds__(256, 2)
void k_pool_l2(const float* __restrict__ U2, const float* __restrict__ Wout,
               const float* __restrict__ msp, const float* __restrict__ shq,
               const bf16* __restrict__ rbm, const bf16* __restrict__ h,
               const float* __restrict__ f2, float* __restrict__ out,
               const int* __restrict__ offsets, const int* __restrict__ elist,
               const int* __restrict__ neighbors)
{
    pool_body<2, 32, 3, 9>(U2, 0.57735026918962576f, Wout + 2048, msp, shq, rbm,
                           h + HOFFc[2], f2, out + HOFFc[2], offsets, elist, neighbors);
}

__global__ __launch_bounds__(256, 2)
void k_pool_l3(const float* __restrict__ U3, const float* __restrict__ Wout,
               const float* __restrict__ msp, const float* __restrict__ shq,
               const bf16* __restrict__ rbm, const bf16* __restrict__ h,
               const float* __restrict__ f3, float* __restrict__ out,
               const int* __restrict__ offsets, const int* __restrict__ elist,
               const int* __restrict__ neighbors)
{
    pool_body<3, 0, 4, 16>(U3, 0.5f, Wout + 3072, msp, shq, rbm,
                           h + HOFFc[3], f3, out + HOFFc[3], offsets, elist, neighbors);
}

// =====================================================================
extern "C" void kernel_launch(void* const* d_in, const int* in_sizes, int n_in,
                              void* d_out, int out_size, void* d_ws, size_t ws_size,
                              hipStream_t stream)
{
    (void)in_sizes; (void)n_in; (void)out_size;

    const float* rb     = (const float*)d_in[0];
    const float* sh0    = (const float*)d_in[1];
    const float* sh1    = (const float*)d_in[2];
    const float* sh2    = (const float*)d_in[3];
    const float* sh3    = (const float*)d_in[4];
    const float* f0     = (const float*)d_in[5];
    const float* f1     = (const float*)d_in[6];
    const float* f2     = (const float*)d_in[7];
    const float* f3     = (const float*)d_in[8];
    const float* U1     = (const float*)d_in[9];
    const float* U2     = (const float*)d_in[10];
    const float* U3     = (const float*)d_in[11];
    const float* gammas = (const float*)d_in[12];
    const float* Win    = (const float*)d_in[13];
    const float* Wout   = (const float*)d_in[14];
    const float* A      = (const float*)d_in[15];
    const float* B0     = (const float*)d_in[16];
    const float* B1     = (const float*)d_in[17];
    const float* B2     = (const float*)d_in[18];
    const float* B3     = (const float*)d_in[19];
    const float* msp    = (const float*)d_in[20];
    const int* centers   = (const int*)d_in[21];
    const int* neighbors = (const int*)d_in[22];

    // ws layout (bytes):
    //   h_bf   @ 0          : 21,120,000 * 2 = 42,240,000
    //   rbm_bf @ 42,240,000 : 25,600,000 * 2 = 51,200,000
    //   shq    @ 93,440,000 :  1,280,000 * 4 =  5,120,000
    //   ints   @ 98,560,000 :    140,001 * 4
    const size_t OFF_RBM = 42240000;
    const size_t OFF_SHQ = 93440000;
    const size_t OFF_INT = 98560000;
    const size_t needed  = OFF_INT + (size_t)140001 * 4;
    if (ws_size < needed) return;

    bf16*  h_bf   = (bf16*)d_ws;
    bf16*  rbm_bf = (bf16*)((char*)d_ws + OFF_RBM);
    float* shq    = (float*)((char*)d_ws + OFF_SHQ);
    int*   ibase  = (int*)((char*)d_ws + OFF_INT);
    int* offsets = ibase;            // 20001
    int* counts  = ibase + 20001;    // 20000
    int* cursor  = ibase + 40001;    // 20000
    int* elist   = ibase + 60001;    // 80000

    hipMemsetAsync(counts, 0, (size_t)40000 * sizeof(int), stream);  // counts + cursor

    k_hist<<<313, 256, 0, stream>>>(centers, counts);
    k_scan<<<1, 1024, 0, stream>>>(counts, offsets);
    k_fill<<<313, 256, 0, stream>>>(centers, offsets, cursor, elist);

    dim3 gA(5000, 4);
    k_norm_in<<<gA, 256, 0, stream>>>(f0, f1, f2, f3, gammas, Win, h_bf);
    k_edgeA<<<1250, 256, 0, stream>>>(rb, sh0, sh1, sh2, sh3, A, B0, B1, B2, B3, rbm_bf, shq);

    float* out = (float*)d_out;
    k_pool_l0<<<5000, 256, 0, stream>>>(U1, Wout, msp, shq, rbm_bf, h_bf, f0, out, offsets, elist, neighbors);
    k_pool_l1<<<5000, 256, 0, stream>>>(U1, Wout, msp, shq, rbm_bf, h_bf, f1, out, offsets, elist, neighbors);
    k_pool_l2<<<5000, 256, 0, stream>>>(U2, Wout, msp, shq, rbm_bf, h_bf, f2, out, offsets, elist, neighbors);
    k_pool_l3<<<5000, 256, 0, stream>>>(U3, Wout, msp, shq, rbm_bf, h_bf, f3, out, offsets, elist, neighbors);
}